// Round 1
// baseline (598.306 us; speedup 1.0000x reference)
//
#include <hip/hip_runtime.h>

// Aggregate = column segment-sum: out[b][g] = sum_{c: sid[c]==g} x[b][c]
// x: [8192, 8192] f32 row-major, sid: [8192] i32 in [0,512), out: [8192, 512] f32.
//
// Strategy: memory-bound streaming. One block (256 thr) owns ROWS=8 full rows.
// LDS acc[8][512] (16 KB -> 4 blocks/CU). Coalesced float4 loads of x; segment
// ids for this thread's (row-invariant) column set are loaded ONCE into 32
// registers and reused across all 8 rows. Scatter via ds_add_f32 (atomicAdd on
// LDS). Epilogue writes the block's 8x512 results directly (no global reduce).

#define NCLS 8192
#define NGRP 512
#define ROWS 8
#define TPB  256

__global__ __launch_bounds__(TPB) void Aggregate_14783277433345_kernel(
    const float* __restrict__ x,
    const int* __restrict__ sid,
    float* __restrict__ out) {
    __shared__ float acc[ROWS][NGRP];

    const int tid  = threadIdx.x;
    const int row0 = blockIdx.x * ROWS;

    // Load this thread's segment ids once: columns (1024*k + 4*tid .. +3), k=0..7.
    // Coalesced int4 loads; 32 VGPRs, reused for all 8 rows.
    int4 s[8];
#pragma unroll
    for (int k = 0; k < 8; ++k) {
        s[k] = *reinterpret_cast<const int4*>(sid + k * 1024 + tid * 4);
    }

    // Zero accumulators (d_ws/d_out are poisoned 0xAA; LDS is uninitialized).
#pragma unroll
    for (int i = tid; i < ROWS * NGRP; i += TPB)
        reinterpret_cast<float*>(acc)[i] = 0.0f;
    __syncthreads();

#pragma unroll 2
    for (int r = 0; r < ROWS; ++r) {
        const float* xrow = x + (size_t)(row0 + r) * NCLS;
#pragma unroll
        for (int k = 0; k < 8; ++k) {
            float4 v = *reinterpret_cast<const float4*>(xrow + k * 1024 + tid * 4);
            atomicAdd(&acc[r][s[k].x], v.x);
            atomicAdd(&acc[r][s[k].y], v.y);
            atomicAdd(&acc[r][s[k].z], v.z);
            atomicAdd(&acc[r][s[k].w], v.w);
        }
    }
    __syncthreads();

    // Coalesced epilogue: 8*512 = 4096 floats, 16 per thread.
#pragma unroll
    for (int i = tid; i < ROWS * NGRP; i += TPB) {
        const int r = i >> 9;         // i / 512
        const int g = i & (NGRP - 1); // i % 512
        out[(size_t)(row0 + r) * NGRP + g] = acc[r][g];
    }
}

extern "C" void kernel_launch(void* const* d_in, const int* in_sizes, int n_in,
                              void* d_out, int out_size, void* d_ws, size_t ws_size,
                              hipStream_t stream) {
    const float* x   = (const float*)d_in[0];
    const int*   sid = (const int*)d_in[1];
    float*       out = (float*)d_out;

    const int batch  = in_sizes[0] / NCLS;   // 8192
    const int blocks = batch / ROWS;         // 1024

    Aggregate_14783277433345_kernel<<<blocks, TPB, 0, stream>>>(x, sid, out);
}

// Round 2
// 431.686 us; speedup vs baseline: 1.3860x; 1.3860x over previous
//
#include <hip/hip_runtime.h>

// Aggregate = column segment-sum: out[b][g] = sum_{c: sid[c]==g} x[b][c]
// x: [8192, 8192] f32, sid: [8192] i32 in [0,512), out: [8192, 512] f32.
//
// R1 lesson: LDS atomicAdd scatter is lane-serial (~200 cyc/wave-inst) on the
// shared per-CU LDS atomic unit -> 341us with ALL pipes idle. Fix: scatter->
// gather. Build CSR (columns sorted by group) with cheap global atomics, then
// each block stages a full row in LDS; each thread owns 2 groups and gathers
// its ~32 columns with plain ds_read (no atomics). Register double-buffer
// prefetches the next row during compute.

#define NCLS 8192
#define NGRP 512
#define ROWS 8
#define TPB  256

// d_ws layout (ints): hist[512] @0, offs[513] @512, curs[512] @1088, cols[8192] @1600

__global__ __launch_bounds__(512) void k_hist(const int* __restrict__ sid,
                                              int* __restrict__ hist) {
    int i = blockIdx.x * 512 + threadIdx.x;
    atomicAdd(&hist[sid[i]], 1);
}

__global__ __launch_bounds__(512) void k_scan(const int* __restrict__ hist,
                                              int* __restrict__ offs,
                                              int* __restrict__ curs) {
    __shared__ int tmp[NGRP];
    const int t = threadIdx.x;
    const int h = hist[t];
    tmp[t] = h;
    __syncthreads();
    for (int off = 1; off < NGRP; off <<= 1) {
        int v = tmp[t];
        int u = (t >= off) ? tmp[t - off] : 0;
        __syncthreads();
        tmp[t] = v + u;
        __syncthreads();
    }
    int excl = tmp[t] - h;   // exclusive prefix sum
    offs[t] = excl;
    curs[t] = excl;
    if (t == NGRP - 1) offs[NGRP] = NCLS;
}

__global__ __launch_bounds__(512) void k_scatter(const int* __restrict__ sid,
                                                 int* __restrict__ curs,
                                                 int* __restrict__ cols) {
    int c = blockIdx.x * 512 + threadIdx.x;
    int g = sid[c];
    int pos = atomicAdd(&curs[g], 1);  // order within group irrelevant (sum)
    cols[pos] = c;
}

__global__ __launch_bounds__(TPB) void k_main(const float* __restrict__ x,
                                              const int* __restrict__ cols,
                                              const int* __restrict__ offs,
                                              float* __restrict__ out) {
    __shared__ float rowb[NCLS];             // 32 KB: one full row
    __shared__ unsigned short col16[NCLS];   // 16 KB: CSR column ids (u16)
    const int tid  = threadIdx.x;
    const int row0 = blockIdx.x * ROWS;

    // Cache CSR column list in LDS (u16: col < 8192).
    for (int i = tid; i < NCLS; i += TPB) col16[i] = (unsigned short)cols[i];

    // Thread owns groups 2*tid and 2*tid+1.
    const int s0 = offs[2 * tid];
    const int e0 = offs[2 * tid + 1];
    const int e1 = offs[2 * tid + 2];

    // Preload row 0 into registers (coalesced float4).
    float4 v[8];
    {
        const float* xr = x + (size_t)row0 * NCLS;
#pragma unroll
        for (int k = 0; k < 8; ++k)
            v[k] = *reinterpret_cast<const float4*>(xr + k * 1024 + tid * 4);
    }
    __syncthreads();  // col16 ready; rowb free
#pragma unroll
    for (int k = 0; k < 8; ++k)
        *reinterpret_cast<float4*>(&rowb[k * 1024 + tid * 4]) = v[k];

    for (int r = 0; r < ROWS; ++r) {
        __syncthreads();  // rowb for row r visible to all

        // Prefetch row r+1 into registers while computing row r from LDS.
        if (r + 1 < ROWS) {
            const float* xr = x + (size_t)(row0 + r + 1) * NCLS;
#pragma unroll
            for (int k = 0; k < 8; ++k)
                v[k] = *reinterpret_cast<const float4*>(xr + k * 1024 + tid * 4);
        }

        float sum0 = 0.f, sum1 = 0.f;
        for (int p = s0; p < e0; ++p) sum0 += rowb[col16[p]];
        for (int p = e0; p < e1; ++p) sum1 += rowb[col16[p]];

        float2 o; o.x = sum0; o.y = sum1;
        *reinterpret_cast<float2*>(out + (size_t)(row0 + r) * NGRP + 2 * tid) = o;

        __syncthreads();  // all reads of rowb done before overwrite
        if (r + 1 < ROWS) {
#pragma unroll
            for (int k = 0; k < 8; ++k)
                *reinterpret_cast<float4*>(&rowb[k * 1024 + tid * 4]) = v[k];
        }
    }
}

extern "C" void kernel_launch(void* const* d_in, const int* in_sizes, int n_in,
                              void* d_out, int out_size, void* d_ws, size_t ws_size,
                              hipStream_t stream) {
    const float* x   = (const float*)d_in[0];
    const int*   sid = (const int*)d_in[1];
    float*       out = (float*)d_out;

    int* ws   = (int*)d_ws;
    int* hist = ws;
    int* offs = ws + 512;
    int* curs = ws + 1088;
    int* cols = ws + 1600;

    const int batch  = in_sizes[0] / NCLS;   // 8192
    const int blocks = batch / ROWS;         // 1024

    hipMemsetAsync(hist, 0, NGRP * sizeof(int), stream);
    k_hist<<<NCLS / 512, 512, 0, stream>>>(sid, hist);
    k_scan<<<1, NGRP, 0, stream>>>(hist, offs, curs);
    k_scatter<<<NCLS / 512, 512, 0, stream>>>(sid, curs, cols);
    k_main<<<blocks, TPB, 0, stream>>>(x, cols, offs, out);
}

// Round 3
// 362.089 us; speedup vs baseline: 1.6524x; 1.1922x over previous
//
#include <hip/hip_runtime.h>

// Aggregate = column segment-sum: out[b][g] = sum_{c: sid[c]==g} x[b][c]
// x: [8192, 8192] f32, sid: [8192] i32 in [0,512), out: [8192, 512] f32.
//
// R1: LDS atomic scatter = lane-serial atomic unit, 341us, all pipes idle.
// R2: CSR gather, 167us but 4x off HBM floor: 2 barriers/row with 2 blocks/CU
//     serialize phases; WRITE_SIZE showed 257MB (x-sized) phantom writes.
// R3: (a) nontemporal loads for x / stores for out (zero reuse -> bypass);
//     (b) row-PAIR processing: one col16 read feeds 2 row buffers (half the
//         index traffic, 2x accumulator ILP); (c) 1 barrier/row net;
//     (d) ROWS=16 -> 512 blocks = exactly 2 resident/CU, no tail.
// LDS: rowb[2][8192] f32 (64KB) + col16[8192] u16 (16KB) = 80KB -> 2 blocks/CU.

#define NCLS 8192
#define NGRP 512
#define ROWS 16
#define TPB  256

typedef float  vf4 __attribute__((ext_vector_type(4)));
typedef float  vf2 __attribute__((ext_vector_type(2)));

// d_ws layout (ints): hist[512] @0, offs[513] @512, curs[512] @1088, cols[8192] @1600

__global__ __launch_bounds__(512) void k_hist(const int* __restrict__ sid,
                                              int* __restrict__ hist) {
    int i = blockIdx.x * 512 + threadIdx.x;
    atomicAdd(&hist[sid[i]], 1);
}

__global__ __launch_bounds__(512) void k_scan(const int* __restrict__ hist,
                                              int* __restrict__ offs,
                                              int* __restrict__ curs) {
    __shared__ int tmp[NGRP];
    const int t = threadIdx.x;
    const int h = hist[t];
    tmp[t] = h;
    __syncthreads();
    for (int off = 1; off < NGRP; off <<= 1) {
        int v = tmp[t];
        int u = (t >= off) ? tmp[t - off] : 0;
        __syncthreads();
        tmp[t] = v + u;
        __syncthreads();
    }
    int excl = tmp[t] - h;   // exclusive prefix sum
    offs[t] = excl;
    curs[t] = excl;
    if (t == NGRP - 1) offs[NGRP] = NCLS;
}

__global__ __launch_bounds__(512) void k_scatter(const int* __restrict__ sid,
                                                 int* __restrict__ curs,
                                                 int* __restrict__ cols) {
    int c = blockIdx.x * 512 + threadIdx.x;
    int g = sid[c];
    int pos = atomicAdd(&curs[g], 1);  // order within group irrelevant (sum)
    cols[pos] = c;
}

__global__ __launch_bounds__(TPB) void k_main(const float* __restrict__ x,
                                              const int* __restrict__ cols,
                                              const int* __restrict__ offs,
                                              float* __restrict__ out) {
    __shared__ float rowb[2][NCLS];          // 64 KB: row pair
    __shared__ unsigned short col16[NCLS];   // 16 KB: CSR column ids (u16)
    const int tid  = threadIdx.x;
    const int row0 = blockIdx.x * ROWS;

    // Cache CSR column list in LDS (u16), vectorized: 8 int4 loads/thread.
    for (int i = tid; i < NCLS / 4; i += TPB) {
        int4 c = reinterpret_cast<const int4*>(cols)[i];
        ushort4 u;
        u.x = (unsigned short)c.x; u.y = (unsigned short)c.y;
        u.z = (unsigned short)c.z; u.w = (unsigned short)c.w;
        *reinterpret_cast<ushort4*>(&col16[4 * i]) = u;
    }

    // Thread owns groups 2*tid and 2*tid+1.
    const int s0 = offs[2 * tid];
    const int e0 = offs[2 * tid + 1];
    const int e1 = offs[2 * tid + 2];

    // Preload pair 0 (nontemporal: x has zero reuse).
    vf4 v[2][8];
#pragma unroll
    for (int rr = 0; rr < 2; ++rr) {
        const float* xr = x + (size_t)(row0 + rr) * NCLS;
#pragma unroll
        for (int k = 0; k < 8; ++k)
            v[rr][k] = __builtin_nontemporal_load(
                reinterpret_cast<const vf4*>(xr + k * 1024 + tid * 4));
    }
    __syncthreads();  // col16 ready
#pragma unroll
    for (int rr = 0; rr < 2; ++rr)
#pragma unroll
        for (int k = 0; k < 8; ++k)
            *reinterpret_cast<vf4*>(&rowb[rr][k * 1024 + tid * 4]) = v[rr][k];

    const int PAIRS = ROWS / 2;
    for (int rp = 0; rp < PAIRS; ++rp) {
        __syncthreads();  // rowb pair visible to all

        // Prefetch next pair while gathering this one.
        if (rp + 1 < PAIRS) {
#pragma unroll
            for (int rr = 0; rr < 2; ++rr) {
                const float* xr = x + (size_t)(row0 + 2 * rp + 2 + rr) * NCLS;
#pragma unroll
                for (int k = 0; k < 8; ++k)
                    v[rr][k] = __builtin_nontemporal_load(
                        reinterpret_cast<const vf4*>(xr + k * 1024 + tid * 4));
            }
        }

        // Gather: one col16 read feeds both rows (4 independent accumulators).
        float s00 = 0.f, s01 = 0.f, s10 = 0.f, s11 = 0.f;
        for (int p = s0; p < e0; ++p) {
            const int c = col16[p];
            s00 += rowb[0][c];
            s10 += rowb[1][c];
        }
        for (int p = e0; p < e1; ++p) {
            const int c = col16[p];
            s01 += rowb[0][c];
            s11 += rowb[1][c];
        }

        {
            vf2 o0; o0.x = s00; o0.y = s01;
            vf2 o1; o1.x = s10; o1.y = s11;
            float* op0 = out + (size_t)(row0 + 2 * rp) * NGRP + 2 * tid;
            float* op1 = op0 + NGRP;
            __builtin_nontemporal_store(o0, reinterpret_cast<vf2*>(op0));
            __builtin_nontemporal_store(o1, reinterpret_cast<vf2*>(op1));
        }

        __syncthreads();  // all reads of rowb done before overwrite
        if (rp + 1 < PAIRS) {
#pragma unroll
            for (int rr = 0; rr < 2; ++rr)
#pragma unroll
                for (int k = 0; k < 8; ++k)
                    *reinterpret_cast<vf4*>(&rowb[rr][k * 1024 + tid * 4]) = v[rr][k];
        }
    }
}

extern "C" void kernel_launch(void* const* d_in, const int* in_sizes, int n_in,
                              void* d_out, int out_size, void* d_ws, size_t ws_size,
                              hipStream_t stream) {
    const float* x   = (const float*)d_in[0];
    const int*   sid = (const int*)d_in[1];
    float*       out = (float*)d_out;

    int* ws   = (int*)d_ws;
    int* hist = ws;
    int* offs = ws + 512;
    int* curs = ws + 1088;
    int* cols = ws + 1600;

    const int batch  = in_sizes[0] / NCLS;   // 8192
    const int blocks = batch / ROWS;         // 512

    hipMemsetAsync(hist, 0, NGRP * sizeof(int), stream);
    k_hist<<<NCLS / 512, 512, 0, stream>>>(sid, hist);
    k_scan<<<1, NGRP, 0, stream>>>(hist, offs, curs);
    k_scatter<<<NCLS / 512, 512, 0, stream>>>(sid, curs, cols);
    k_main<<<blocks, TPB, 0, stream>>>(x, cols, offs, out);
}